// Round 2
// baseline (912.382 us; speedup 1.0000x reference)
//
#include <hip/hip_runtime.h>
#include <hip/hip_bf16.h>

#define SEQ 4096
#define BATCH 2
#define HEADS 16
#define DHEAD 64
#define HID 1024

typedef unsigned short ushort_t;
typedef __attribute__((ext_vector_type(8))) short short8;
typedef __attribute__((ext_vector_type(4))) float f32x4;

__device__ __forceinline__ ushort_t f2b(float f) {
  unsigned u = __builtin_bit_cast(unsigned, f);
  unsigned r = 0x7fffu + ((u >> 16) & 1u);
  return (ushort_t)((u + r) >> 16);
}

__device__ __forceinline__ void gload16(const void* g, void* l) {
  __builtin_amdgcn_global_load_lds((const __attribute__((address_space(1))) void*)g,
                                   (__attribute__((address_space(3))) void*)l, 16, 0, 0);
}

__device__ __forceinline__ f32x4 mfma_bf16(short8 a, short8 b, f32x4 c) {
  return __builtin_amdgcn_mfma_f32_16x16x32_bf16(a, b, c, 0, 0, 0);
}

// ---------------- fp32 -> bf16 elementwise (vectorized) ----------------
__global__ void cvt_kernel(const float* __restrict__ in, ushort_t* __restrict__ out, int n4) {
  int i = blockIdx.x * blockDim.x + threadIdx.x;
  if (i >= n4) return;
  float4 v = reinterpret_cast<const float4*>(in)[i];
  ushort4 o;
  o.x = f2b(v.x); o.y = f2b(v.y); o.z = f2b(v.z); o.w = f2b(v.w);
  reinterpret_cast<ushort4*>(out)[i] = o;
}

// ---------------- transpose + convert: in[rows][cols] f32 -> out[cols][rows] bf16 ----------------
__global__ void transpose_cvt_kernel(const float* __restrict__ in, ushort_t* __restrict__ out,
                                     int rows, int cols) {
  __shared__ float tile[32][33];
  int tx = threadIdx.x & 31, ty = threadIdx.x >> 5;  // 256 threads: ty 0..7
  int r0 = blockIdx.y * 32, c0 = blockIdx.x * 32;
#pragma unroll
  for (int i = 0; i < 32; i += 8)
    tile[ty + i][tx] = in[(size_t)(r0 + ty + i) * cols + c0 + tx];
  __syncthreads();
#pragma unroll
  for (int i = 0; i < 32; i += 8)
    out[(size_t)(c0 + ty + i) * rows + r0 + tx] = f2b(tile[tx][ty + i]);
}

// ---------------- bf16 GEMM: C = A[M][K] * BT[N][K]^T ----------------
// LDS tiles are [row][64] bf16 (128B rows, 8x16B chunks); reads XOR-swizzled by
// chunk ^= row&7, staged via pre-swizzled global source (linear LDS dest).
// MODE 0: scatter-write q/k/vT bf16.  MODE 1: write fp32 C.
template <int MODE>
__global__ __launch_bounds__(256, 2)
void gemm_kernel(const ushort_t* __restrict__ A, const ushort_t* __restrict__ BT,
                 int M, int N, int K,
                 ushort_t* __restrict__ qg, ushort_t* __restrict__ kg,
                 ushort_t* __restrict__ vTg, float* __restrict__ outf) {
  __shared__ ushort_t lA[128 * 64];
  __shared__ ushort_t lB[128 * 64];
  int tid = threadIdx.x;
  int lane = tid & 63, w = tid >> 6;
  int m0 = blockIdx.x * 128, n0 = blockIdx.y * 128;
  int wr = (w >> 1) * 64, wc = (w & 1) * 64;
  int lr = lane & 15, lg = lane >> 4;

  const f32x4 z4 = {0.f, 0.f, 0.f, 0.f};
  f32x4 acc[4][4];
#pragma unroll
  for (int m = 0; m < 4; ++m)
#pragma unroll
    for (int n = 0; n < 4; ++n) acc[m][n] = z4;

  int ktiles = K >> 6;
  for (int kt = 0; kt < ktiles; ++kt) {
    int k0 = kt << 6;
#pragma unroll
    for (int i = 0; i < 4; ++i) {
      int c = i * 256 + tid;
      int row = c >> 3, cc = c & 7;
      gload16(A + (size_t)(m0 + row) * K + k0 + (cc ^ (row & 7)) * 8, lA + c * 8);
    }
#pragma unroll
    for (int i = 0; i < 4; ++i) {
      int c = i * 256 + tid;
      int row = c >> 3, cc = c & 7;
      gload16(BT + (size_t)(n0 + row) * K + k0 + (cc ^ (row & 7)) * 8, lB + c * 8);
    }
    __syncthreads();
#pragma unroll
    for (int kk = 0; kk < 2; ++kk) {
      short8 a[4], b[4];
#pragma unroll
      for (int m = 0; m < 4; ++m) {
        int row = wr + m * 16 + lr, cc = kk * 4 + lg;
        a[m] = *(const short8*)(lA + row * 64 + (cc ^ (row & 7)) * 8);
      }
#pragma unroll
      for (int n = 0; n < 4; ++n) {
        int row = wc + n * 16 + lr, cc = kk * 4 + lg;
        b[n] = *(const short8*)(lB + row * 64 + (cc ^ (row & 7)) * 8);
      }
      __builtin_amdgcn_s_setprio(1);
#pragma unroll
      for (int m = 0; m < 4; ++m)
#pragma unroll
        for (int n = 0; n < 4; ++n)
          acc[m][n] = mfma_bf16(a[m], b[n], acc[m][n]);
      __builtin_amdgcn_s_setprio(0);
    }
    __syncthreads();
  }

#pragma unroll
  for (int m = 0; m < 4; ++m)
#pragma unroll
    for (int n = 0; n < 4; ++n)
#pragma unroll
      for (int r = 0; r < 4; ++r) {
        int i = m0 + wr + m * 16 + lg * 4 + r;
        int j = n0 + wc + n * 16 + lr;
        float v = acc[m][n][r];
        if (MODE == 0) {
          int mat = j >> 10, rem = j & 1023;
          int h = rem >> 6, d = rem & 63;
          int b = i >> 12, s = i & 4095;
          int bh = b * HEADS + h;
          ushort_t val = f2b(v);
          if (mat == 0)      qg[((size_t)bh * SEQ + s) * DHEAD + d] = val;
          else if (mat == 1) kg[((size_t)bh * SEQ + s) * DHEAD + d] = val;
          else               vTg[((size_t)bh * DHEAD + d) * SEQ + s] = val;
        } else {
          outf[(size_t)i * N + j] = v;
        }
      }
}

// ---------------- flash attention: per block one (b,h, 128-row q tile) ----------------
// LDS: lKP (32 KiB) holds K tile [128][64] during QK^T, then P tile [128][128];
// lV (16 KiB) holds V^T tile [64][128]. Total 48 KiB -> 3 blocks/CU.
// All fragment reads XOR-chunk-swizzled; K/V staged with pre-swizzled global src.
__global__ __launch_bounds__(256, 3)
void attn_kernel(const ushort_t* __restrict__ qg, const ushort_t* __restrict__ kg,
                 const ushort_t* __restrict__ vTg, ushort_t* __restrict__ og) {
  __shared__ ushort_t lKP[128 * 128];
  __shared__ ushort_t lV[64 * 128];

  int bid = blockIdx.x;
  int qt = 31 - (bid >> 5);  // heavy q-tiles dispatched first
  int bh = bid & 31;
  int q0 = qt * 128;
  const ushort_t* Q = qg + (size_t)bh * SEQ * DHEAD;
  const ushort_t* Kp = kg + (size_t)bh * SEQ * DHEAD;
  const ushort_t* Vt = vTg + (size_t)bh * DHEAD * SEQ;

  int tid = threadIdx.x, lane = tid & 63, w = tid >> 6;
  int lr = lane & 15, lg = lane >> 4;

  // stage Q linearly, hoist fragments to registers, then lKP is free for K/P
#pragma unroll
  for (int i = 0; i < 4; ++i) {
    int c = i * 256 + tid;
    gload16(Q + q0 * DHEAD + c * 8, lKP + c * 8);
  }
  __syncthreads();
  short8 qf[2][2];
#pragma unroll
  for (int m = 0; m < 2; ++m)
#pragma unroll
    for (int kk = 0; kk < 2; ++kk)
      qf[m][kk] = *(const short8*)(lKP + (w * 32 + m * 16 + lr) * 64 + kk * 32 + lg * 8);
  __syncthreads();

  const f32x4 z4 = {0.f, 0.f, 0.f, 0.f};
  float mrow[2][4], lsum[2][4];
  f32x4 o[2][4];
#pragma unroll
  for (int m = 0; m < 2; ++m)
#pragma unroll
    for (int r = 0; r < 4; ++r) { mrow[m][r] = -1e30f; lsum[m][r] = 0.f; }
#pragma unroll
  for (int m = 0; m < 2; ++m)
#pragma unroll
    for (int n = 0; n < 4; ++n) o[m][n] = z4;

  for (int jt = 0; jt <= qt; ++jt) {
    int j0 = jt * 128;
    // stage K [128][64] into lKP, V^T [64][128] into lV (pre-swizzled sources)
#pragma unroll
    for (int i = 0; i < 4; ++i) {
      int c = i * 256 + tid;
      int row = c >> 3, cc = c & 7;
      gload16(Kp + (size_t)(j0 + row) * DHEAD + (cc ^ (row & 7)) * 8, lKP + c * 8);
    }
#pragma unroll
    for (int i = 0; i < 4; ++i) {
      int c = i * 256 + tid;
      int d = c >> 4, cc = c & 15;
      gload16(Vt + (size_t)d * SEQ + j0 + (cc ^ (d & 15)) * 8, lV + c * 8);
    }
    __syncthreads();

    // S = Q K^T  (swizzled K reads)
    f32x4 s[2][8];
#pragma unroll
    for (int m = 0; m < 2; ++m)
#pragma unroll
      for (int n = 0; n < 8; ++n) s[m][n] = z4;
#pragma unroll
    for (int kk = 0; kk < 2; ++kk) {
#pragma unroll
      for (int nt = 0; nt < 8; ++nt) {
        int row = nt * 16 + lr, cc = kk * 4 + lg;
        short8 b = *(const short8*)(lKP + row * 64 + (cc ^ (row & 7)) * 8);
        __builtin_amdgcn_s_setprio(1);
#pragma unroll
        for (int m = 0; m < 2; ++m) s[m][nt] = mfma_bf16(qf[m][kk], b, s[m][nt]);
        __builtin_amdgcn_s_setprio(0);
      }
    }
    __syncthreads();  // all waves done reading K before P overwrites lKP

    // scale + causal mask
    bool diag = (jt == qt);
#pragma unroll
    for (int m = 0; m < 2; ++m)
#pragma unroll
      for (int nt = 0; nt < 8; ++nt)
#pragma unroll
        for (int r = 0; r < 4; ++r) {
          float v = s[m][nt][r] * 0.125f;
          if (diag && (j0 + nt * 16 + lr) > (q0 + w * 32 + m * 16 + lg * 4 + r)) v = -1e30f;
          s[m][nt][r] = v;
        }

    // online softmax (each lane-pair group reduces over 8 col-tiles + 16 lanes)
#pragma unroll
    for (int m = 0; m < 2; ++m)
#pragma unroll
      for (int r = 0; r < 4; ++r) {
        float mx = s[m][0][r];
#pragma unroll
        for (int nt = 1; nt < 8; ++nt) mx = fmaxf(mx, s[m][nt][r]);
        mx = fmaxf(mx, __shfl_xor(mx, 1));
        mx = fmaxf(mx, __shfl_xor(mx, 2));
        mx = fmaxf(mx, __shfl_xor(mx, 4));
        mx = fmaxf(mx, __shfl_xor(mx, 8));
        float mo = mrow[m][r];
        float mn = fmaxf(mo, mx);
        float al = __expf(mo - mn);
        mrow[m][r] = mn;
        float rs = 0.f;
#pragma unroll
        for (int nt = 0; nt < 8; ++nt) {
          float p = __expf(s[m][nt][r] - mn);
          s[m][nt][r] = p;
          rs += p;
        }
        rs += __shfl_xor(rs, 1);
        rs += __shfl_xor(rs, 2);
        rs += __shfl_xor(rs, 4);
        rs += __shfl_xor(rs, 8);
        lsum[m][r] = lsum[m][r] * al + rs;
#pragma unroll
        for (int nd = 0; nd < 4; ++nd) o[m][nd][r] *= al;
      }

    // P -> lKP (bf16), swizzled write: [128][128] halfwords, 16 chunks/row
#pragma unroll
    for (int m = 0; m < 2; ++m)
#pragma unroll
      for (int nt = 0; nt < 8; ++nt)
#pragma unroll
        for (int r = 0; r < 4; ++r) {
          int row = w * 32 + m * 16 + lg * 4 + r;
          int col = nt * 16 + lr;
          lKP[row * 128 + ((col >> 3) ^ (row & 15)) * 8 + (col & 7)] = f2b(s[m][nt][r]);
        }
    __syncthreads();

    // O += P V  (swizzled P and V reads)
#pragma unroll
    for (int kk = 0; kk < 4; ++kk) {
      short8 a[2];
#pragma unroll
      for (int m = 0; m < 2; ++m) {
        int row = w * 32 + m * 16 + lr, cc = kk * 4 + lg;
        a[m] = *(const short8*)(lKP + row * 128 + (cc ^ (row & 15)) * 8);
      }
#pragma unroll
      for (int nd = 0; nd < 4; ++nd) {
        int row = nd * 16 + lr, cc = kk * 4 + lg;
        short8 b = *(const short8*)(lV + row * 128 + (cc ^ (row & 15)) * 8);
        __builtin_amdgcn_s_setprio(1);
#pragma unroll
        for (int m = 0; m < 2; ++m) o[m][nd] = mfma_bf16(a[m], b, o[m][nd]);
        __builtin_amdgcn_s_setprio(0);
      }
    }
    __syncthreads();
  }

  // epilogue: O /= l, write bf16 to [B][S][H*D]
  int b = bh >> 4, h = bh & 15;
#pragma unroll
  for (int m = 0; m < 2; ++m)
#pragma unroll
    for (int nd = 0; nd < 4; ++nd)
#pragma unroll
      for (int r = 0; r < 4; ++r) {
        int srow = q0 + w * 32 + m * 16 + lg * 4 + r;
        int col = h * 64 + nd * 16 + lr;
        float val = o[m][nd][r] / lsum[m][r];
        og[((size_t)b * SEQ + srow) * HID + col] = f2b(val);
      }
}

extern "C" void kernel_launch(void* const* d_in, const int* in_sizes, int n_in,
                              void* d_out, int out_size, void* d_ws, size_t ws_size,
                              hipStream_t stream) {
  const float* x = (const float*)d_in[0];
  const float* wqkv = (const float*)d_in[1];
  const float* wout = (const float*)d_in[2];
  float* out = (float*)d_out;

  if (ws_size < 75497472u) return;  // need 75.5 MB scratch

  char* ws = (char*)d_ws;
  ushort_t* xb    = (ushort_t*)(ws);               // 8192x1024 bf16 (reused as attn out)
  ushort_t* wqkvT = (ushort_t*)(ws + 16777216);    // 3072x1024
  ushort_t* woutT = (ushort_t*)(ws + 23068672);    // 1024x1024
  ushort_t* qgb   = (ushort_t*)(ws + 25165824);    // [32][4096][64]
  ushort_t* kgb   = (ushort_t*)(ws + 41943040);    // [32][4096][64]
  ushort_t* vTb   = (ushort_t*)(ws + 58720256);    // [32][64][4096]
  ushort_t* ob    = xb;

  cvt_kernel<<<dim3(8192), dim3(256), 0, stream>>>(x, xb, 2097152);
  transpose_cvt_kernel<<<dim3(96, 32), dim3(256), 0, stream>>>(wqkv, wqkvT, 1024, 3072);
  transpose_cvt_kernel<<<dim3(32, 32), dim3(256), 0, stream>>>(wout, woutT, 1024, 1024);
  gemm_kernel<0><<<dim3(64, 24), dim3(256), 0, stream>>>(xb, wqkvT, 8192, 3072, 1024,
                                                         qgb, kgb, vTb, nullptr);
  attn_kernel<<<dim3(1024), dim3(256), 0, stream>>>(qgb, kgb, vTb, ob);
  gemm_kernel<1><<<dim3(64, 8), dim3(256), 0, stream>>>(ob, woutT, 8192, 1024, 1024,
                                                        nullptr, nullptr, nullptr, out);
}

// Round 3
// 294.404 us; speedup vs baseline: 3.0991x; 3.0991x over previous
//
#include <hip/hip_runtime.h>
#include <hip/hip_bf16.h>

#define SEQ 4096
#define BATCH 2
#define HEADS 16
#define DHEAD 64
#define HID 1024

typedef unsigned short ushort_t;
typedef __attribute__((ext_vector_type(8))) short short8;
typedef __attribute__((ext_vector_type(4))) float f32x4;

__device__ __forceinline__ ushort_t f2b(float f) {
  unsigned u = __builtin_bit_cast(unsigned, f);
  unsigned r = 0x7fffu + ((u >> 16) & 1u);
  return (ushort_t)((u + r) >> 16);
}

__device__ __forceinline__ void gload16(const void* g, void* l) {
  __builtin_amdgcn_global_load_lds((const __attribute__((address_space(1))) void*)g,
                                   (__attribute__((address_space(3))) void*)l, 16, 0, 0);
}

__device__ __forceinline__ f32x4 mfma_bf16(short8 a, short8 b, f32x4 c) {
  return __builtin_amdgcn_mfma_f32_16x16x32_bf16(a, b, c, 0, 0, 0);
}

// ---------------- fp32 -> bf16 elementwise (vectorized) ----------------
__global__ void cvt_kernel(const float* __restrict__ in, ushort_t* __restrict__ out, int n4) {
  int i = blockIdx.x * blockDim.x + threadIdx.x;
  if (i >= n4) return;
  float4 v = reinterpret_cast<const float4*>(in)[i];
  ushort4 o;
  o.x = f2b(v.x); o.y = f2b(v.y); o.z = f2b(v.z); o.w = f2b(v.w);
  reinterpret_cast<ushort4*>(out)[i] = o;
}

// ---------------- transpose + convert: in[rows][cols] f32 -> out[cols][rows] bf16 ----------------
__global__ void transpose_cvt_kernel(const float* __restrict__ in, ushort_t* __restrict__ out,
                                     int rows, int cols) {
  __shared__ float tile[32][33];
  int tx = threadIdx.x & 31, ty = threadIdx.x >> 5;
  int r0 = blockIdx.y * 32, c0 = blockIdx.x * 32;
#pragma unroll
  for (int i = 0; i < 32; i += 8)
    tile[ty + i][tx] = in[(size_t)(r0 + ty + i) * cols + c0 + tx];
  __syncthreads();
#pragma unroll
  for (int i = 0; i < 32; i += 8)
    out[(size_t)(c0 + ty + i) * rows + r0 + tx] = f2b(tile[tx][ty + i]);
}

// ---------------- bf16 GEMM: C = A[M][K] * BT[N][K]^T ----------------
// MODE 0: scatter-write q(*0.125)/k/vT bf16.  MODE 1: write fp32 C.
template <int MODE>
__global__ __launch_bounds__(256, 2)
void gemm_kernel(const ushort_t* __restrict__ A, const ushort_t* __restrict__ BT,
                 int M, int N, int K,
                 ushort_t* __restrict__ qg, ushort_t* __restrict__ kg,
                 ushort_t* __restrict__ vTg, float* __restrict__ outf) {
  __shared__ ushort_t lA[128 * 64];
  __shared__ ushort_t lB[128 * 64];
  int tid = threadIdx.x;
  int lane = tid & 63, w = tid >> 6;
  int m0 = blockIdx.x * 128, n0 = blockIdx.y * 128;
  int wr = (w >> 1) * 64, wc = (w & 1) * 64;
  int lr = lane & 15, lg = lane >> 4;

  const f32x4 z4 = {0.f, 0.f, 0.f, 0.f};
  f32x4 acc[4][4];
#pragma unroll
  for (int m = 0; m < 4; ++m)
#pragma unroll
    for (int n = 0; n < 4; ++n) acc[m][n] = z4;

  int ktiles = K >> 6;
  for (int kt = 0; kt < ktiles; ++kt) {
    int k0 = kt << 6;
#pragma unroll
    for (int i = 0; i < 4; ++i) {
      int c = i * 256 + tid;
      int row = c >> 3, cc = c & 7;
      gload16(A + (size_t)(m0 + row) * K + k0 + (cc ^ (row & 7)) * 8, lA + c * 8);
    }
#pragma unroll
    for (int i = 0; i < 4; ++i) {
      int c = i * 256 + tid;
      int row = c >> 3, cc = c & 7;
      gload16(BT + (size_t)(n0 + row) * K + k0 + (cc ^ (row & 7)) * 8, lB + c * 8);
    }
    __syncthreads();
#pragma unroll
    for (int kk = 0; kk < 2; ++kk) {
      short8 a[4], b[4];
#pragma unroll
      for (int m = 0; m < 4; ++m) {
        int row = wr + m * 16 + lr, cc = kk * 4 + lg;
        a[m] = *(const short8*)(lA + row * 64 + ((cc ^ (row & 7)) << 3));
      }
#pragma unroll
      for (int n = 0; n < 4; ++n) {
        int row = wc + n * 16 + lr, cc = kk * 4 + lg;
        b[n] = *(const short8*)(lB + row * 64 + ((cc ^ (row & 7)) << 3));
      }
      __builtin_amdgcn_s_setprio(1);
#pragma unroll
      for (int m = 0; m < 4; ++m)
#pragma unroll
        for (int n = 0; n < 4; ++n)
          acc[m][n] = mfma_bf16(a[m], b[n], acc[m][n]);
      __builtin_amdgcn_s_setprio(0);
    }
    __syncthreads();
  }

#pragma unroll
  for (int m = 0; m < 4; ++m)
#pragma unroll
    for (int n = 0; n < 4; ++n)
#pragma unroll
      for (int r = 0; r < 4; ++r) {
        int i = m0 + wr + m * 16 + lg * 4 + r;
        int j = n0 + wc + n * 16 + lr;
        float v = acc[m][n][r];
        if (MODE == 0) {
          int mat = j >> 10, rem = j & 1023;
          int h = rem >> 6, d = rem & 63;
          int b = i >> 12, s = i & 4095;
          int bh = b * HEADS + h;
          ushort_t val = f2b(mat == 0 ? v * 0.125f : v);  // fold 1/sqrt(64) into Q
          if (mat == 0)      qg[((size_t)bh * SEQ + s) * DHEAD + d] = val;
          else if (mat == 1) kg[((size_t)bh * SEQ + s) * DHEAD + d] = val;
          else               vTg[((size_t)bh * DHEAD + d) * SEQ + s] = val;
        } else {
          outf[(size_t)i * N + j] = v;
        }
      }
}

// ---------------- flash attention, swapped-QK^T (S^T) form ----------------
// Per block: (b,h, 128 q-rows), 4 waves x 32 q-rows. KV tile 128.
// lK 16KB | lV 16KB | lP 32KB (P[q][k], wave-private rows) = 64KB -> 2 blocks/CU.
// S^T = mfma(K,Q): lane holds col q=lr, rows k=lg*4+r (+16*kt) -> in-lane softmax,
// P-write as ds_write_b64 (4 consecutive k per reg quad). 2 barriers/iter.
__global__ __launch_bounds__(256, 2)
void attn_kernel(const ushort_t* __restrict__ qg, const ushort_t* __restrict__ kg,
                 const ushort_t* __restrict__ vTg, ushort_t* __restrict__ og) {
  __shared__ ushort_t lK[128 * 64];
  __shared__ ushort_t lV[64 * 128];
  __shared__ ushort_t lP[128 * 128];

  int bid = blockIdx.x;
  int wg = (bid & 7) * 128 + (bid >> 3);  // XCD-chunked: each XCD owns 4 bh
  int qt = 31 - (wg & 31);                // heavy q-tiles first within each bh
  int bh = wg >> 5;
  int q0 = qt * 128;
  const ushort_t* Q = qg + (size_t)bh * SEQ * DHEAD;
  const ushort_t* Kp = kg + (size_t)bh * SEQ * DHEAD;
  const ushort_t* Vt = vTg + (size_t)bh * DHEAD * SEQ;

  int tid = threadIdx.x, lane = tid & 63, w = tid >> 6;
  int lr = lane & 15, lg = lane >> 4;

  // stage Q into lP (swizzled like K), hoist fragments, then lP becomes P-space
#pragma unroll
  for (int i = 0; i < 4; ++i) {
    int c = i * 256 + tid;
    int row = c >> 3, cc = c & 7;
    gload16(Q + (size_t)(q0 + row) * DHEAD + (cc ^ (row & 7)) * 8, lP + c * 8);
  }
  __syncthreads();
  short8 qf[2][2];
#pragma unroll
  for (int qm = 0; qm < 2; ++qm)
#pragma unroll
    for (int kk = 0; kk < 2; ++kk) {
      int row = w * 32 + qm * 16 + lr;
      qf[qm][kk] = *(const short8*)(lP + row * 64 + (((kk * 4 + lg) ^ (row & 7)) << 3));
    }
  // (iter-0 post-stage barrier protects lP before first P-write)

  float mrow[2], lsum[2];
  f32x4 o[2][4];
  const f32x4 z4 = {0.f, 0.f, 0.f, 0.f};
#pragma unroll
  for (int qm = 0; qm < 2; ++qm) { mrow[qm] = -1e30f; lsum[qm] = 0.f; }
#pragma unroll
  for (int m = 0; m < 2; ++m)
#pragma unroll
    for (int n = 0; n < 4; ++n) o[m][n] = z4;

  for (int jt = 0; jt <= qt; ++jt) {
    int j0 = jt * 128;
    // stage K [128][64] and V^T [64][128] (pre-swizzled global sources)
#pragma unroll
    for (int i = 0; i < 4; ++i) {
      int c = i * 256 + tid;
      int row = c >> 3, cc = c & 7;
      gload16(Kp + (size_t)(j0 + row) * DHEAD + (cc ^ (row & 7)) * 8, lK + c * 8);
    }
#pragma unroll
    for (int i = 0; i < 4; ++i) {
      int c = i * 256 + tid;
      int d = c >> 4, cc = c & 15;
      gload16(Vt + (size_t)d * SEQ + j0 + (cc ^ (d & 15)) * 8, lV + c * 8);
    }
    __syncthreads();

    // S^T = K Q^T : s[qm][kt], lane holds q-col lr, k-rows lg*4+r (+16kt)
    f32x4 s[2][8];
#pragma unroll
    for (int qm = 0; qm < 2; ++qm)
#pragma unroll
      for (int kt = 0; kt < 8; ++kt) s[qm][kt] = z4;
#pragma unroll
    for (int kk = 0; kk < 2; ++kk) {
#pragma unroll
      for (int kt = 0; kt < 8; ++kt) {
        int row = kt * 16 + lr;
        short8 kf = *(const short8*)(lK + row * 64 + (((kk * 4 + lg) ^ (row & 7)) << 3));
        __builtin_amdgcn_s_setprio(1);
        s[0][kt] = mfma_bf16(kf, qf[0][kk], s[0][kt]);
        s[1][kt] = mfma_bf16(kf, qf[1][kk], s[1][kt]);
        __builtin_amdgcn_s_setprio(0);
      }
    }

    // causal mask (diagonal tile only)
    if (jt == qt) {
#pragma unroll
      for (int qm = 0; qm < 2; ++qm) {
        int qgl = w * 32 + qm * 16 + lr;  // both q,k share base q0==j0 here
#pragma unroll
        for (int kt = 0; kt < 8; ++kt)
#pragma unroll
          for (int r = 0; r < 4; ++r)
            if (kt * 16 + lg * 4 + r > qgl) s[qm][kt][r] = -1e30f;
      }
    }

    // online softmax, in-lane over 32 k + 2 shfls; defer-max (THR=8)
    float alv[2] = {1.f, 1.f};
    int resc = 0;
#pragma unroll
    for (int qm = 0; qm < 2; ++qm) {
      float mx = s[qm][0][0];
#pragma unroll
      for (int kt = 0; kt < 8; ++kt)
#pragma unroll
        for (int r = 0; r < 4; ++r) mx = fmaxf(mx, s[qm][kt][r]);
      mx = fmaxf(mx, __shfl_xor(mx, 16));
      mx = fmaxf(mx, __shfl_xor(mx, 32));
      float mo = mrow[qm];
      if (!__all(mx - mo <= 8.0f)) {
        float mn = fmaxf(mo, mx);
        float al = __expf(mo - mn);
        mrow[qm] = mn;
        lsum[qm] *= al;
        alv[qm] = al;
        resc |= (1 << qm);
      }
      float mloc = mrow[qm];
      float rs = 0.f;
#pragma unroll
      for (int kt = 0; kt < 8; ++kt)
#pragma unroll
        for (int r = 0; r < 4; ++r) {
          float p = __expf(s[qm][kt][r] - mloc);
          s[qm][kt][r] = p;
          rs += p;
        }
      rs += __shfl_xor(rs, 16);
      rs += __shfl_xor(rs, 32);
      lsum[qm] += rs;
    }
    if (resc) {
#pragma unroll
      for (int m = 0; m < 2; ++m)
        if (resc & (1 << m)) {
#pragma unroll
          for (int r = 0; r < 4; ++r) {
            float alo = __shfl(alv[m], (lane & 48) | (lg * 4 + r));
#pragma unroll
            for (int nd = 0; nd < 4; ++nd) o[m][nd][r] *= alo;
          }
        }
    }

    // P-write: lane's reg quad = 4 consecutive k for col q -> ds_write_b64
    // lP layout [q][128 k], chunk-swizzled by (q&15)
#pragma unroll
    for (int qm = 0; qm < 2; ++qm) {
      int q = w * 32 + qm * 16 + lr;
#pragma unroll
      for (int kt = 0; kt < 8; ++kt) {
        ushort4 pw;
        pw.x = f2b(s[qm][kt][0]); pw.y = f2b(s[qm][kt][1]);
        pw.z = f2b(s[qm][kt][2]); pw.w = f2b(s[qm][kt][3]);
        int c = kt * 2 + (lg >> 1);
        *(ushort4*)(lP + q * 128 + (((c ^ (q & 15)) << 3) | ((lg & 1) << 2))) = pw;
      }
    }

    // O += P V (wave-private P rows; compiler orders write->read via lgkmcnt)
#pragma unroll
    for (int kk = 0; kk < 4; ++kk) {
      short8 a[2];
#pragma unroll
      for (int m = 0; m < 2; ++m) {
        int q = w * 32 + m * 16 + lr;
        a[m] = *(const short8*)(lP + q * 128 + (((kk * 4 + lg) ^ (q & 15)) << 3));
      }
#pragma unroll
      for (int nd = 0; nd < 4; ++nd) {
        int row = nd * 16 + lr;
        short8 b = *(const short8*)(lV + row * 128 + (((kk * 4 + lg) ^ (row & 15)) << 3));
        __builtin_amdgcn_s_setprio(1);
        o[0][nd] = mfma_bf16(a[0], b, o[0][nd]);
        o[1][nd] = mfma_bf16(a[1], b, o[1][nd]);
        __builtin_amdgcn_s_setprio(0);
      }
    }
    __syncthreads();  // protect lK/lV (and lP rows) before next stage
  }

  // epilogue: O /= l (l redistributed via shfl), write bf16 [B][S][H*D]
  int b = bh >> 4, h = bh & 15;
#pragma unroll
  for (int m = 0; m < 2; ++m)
#pragma unroll
    for (int r = 0; r < 4; ++r) {
      float ls = __shfl(lsum[m], (lane & 48) | (lg * 4 + r));
      float inv = 1.0f / ls;
      int srow = q0 + w * 32 + m * 16 + lg * 4 + r;
#pragma unroll
      for (int nd = 0; nd < 4; ++nd) {
        int col = h * 64 + nd * 16 + lr;
        og[((size_t)b * SEQ + srow) * HID + col] = f2b(o[m][nd][r] * inv);
      }
    }
}

extern "C" void kernel_launch(void* const* d_in, const int* in_sizes, int n_in,
                              void* d_out, int out_size, void* d_ws, size_t ws_size,
                              hipStream_t stream) {
  const float* x = (const float*)d_in[0];
  const float* wqkv = (const float*)d_in[1];
  const float* wout = (const float*)d_in[2];
  float* out = (float*)d_out;

  if (ws_size < 75497472u) return;  // need 75.5 MB scratch

  char* ws = (char*)d_ws;
  ushort_t* xb    = (ushort_t*)(ws);               // 8192x1024 bf16 (reused as attn out)
  ushort_t* wqkvT = (ushort_t*)(ws + 16777216);    // 3072x1024
  ushort_t* woutT = (ushort_t*)(ws + 23068672);    // 1024x1024
  ushort_t* qgb   = (ushort_t*)(ws + 25165824);    // [32][4096][64]
  ushort_t* kgb   = (ushort_t*)(ws + 41943040);    // [32][4096][64]
  ushort_t* vTb   = (ushort_t*)(ws + 58720256);    // [32][64][4096]
  ushort_t* ob    = xb;

  cvt_kernel<<<dim3(8192), dim3(256), 0, stream>>>(x, xb, 2097152);
  transpose_cvt_kernel<<<dim3(96, 32), dim3(256), 0, stream>>>(wqkv, wqkvT, 1024, 3072);
  transpose_cvt_kernel<<<dim3(32, 32), dim3(256), 0, stream>>>(wout, woutT, 1024, 1024);
  gemm_kernel<0><<<dim3(64, 24), dim3(256), 0, stream>>>(xb, wqkvT, 8192, 3072, 1024,
                                                         qgb, kgb, vTb, nullptr);
  attn_kernel<<<dim3(1024), dim3(256), 0, stream>>>(qgb, kgb, vTb, ob);
  gemm_kernel<1><<<dim3(64, 8), dim3(256), 0, stream>>>(ob, woutT, 8192, 1024, 1024,
                                                        nullptr, nullptr, nullptr, out);
}

// Round 5
// 229.162 us; speedup vs baseline: 3.9814x; 1.2847x over previous
//
#include <hip/hip_runtime.h>
#include <hip/hip_bf16.h>

#define SEQ 4096
#define BATCH 2
#define HEADS 16
#define DHEAD 64
#define HID 1024

typedef unsigned short ushort_t;
typedef __attribute__((ext_vector_type(8))) short short8;
typedef __attribute__((ext_vector_type(4))) float f32x4;

__device__ __forceinline__ float exp2_fast(float x) {
  return __builtin_amdgcn_exp2f(x);  // v_exp_f32 computes 2^x natively
}

__device__ __forceinline__ ushort_t f2b(float f) {
  unsigned u = __builtin_bit_cast(unsigned, f);
  unsigned r = 0x7fffu + ((u >> 16) & 1u);
  return (ushort_t)((u + r) >> 16);
}

__device__ __forceinline__ unsigned cvt_pk_bf16(float lo, float hi) {
  unsigned r;
  asm("v_cvt_pk_bf16_f32 %0, %1, %2" : "=v"(r) : "v"(lo), "v"(hi));
  return r;
}

__device__ __forceinline__ void gload16(const void* g, void* l) {
  __builtin_amdgcn_global_load_lds((const __attribute__((address_space(1))) void*)g,
                                   (__attribute__((address_space(3))) void*)l, 16, 0, 0);
}

__device__ __forceinline__ f32x4 mfma_bf16(short8 a, short8 b, f32x4 c) {
  return __builtin_amdgcn_mfma_f32_16x16x32_bf16(a, b, c, 0, 0, 0);
}

// ---------------- fp32 -> bf16 elementwise (vectorized) ----------------
__global__ void cvt_kernel(const float* __restrict__ in, ushort_t* __restrict__ out, int n4) {
  int i = blockIdx.x * blockDim.x + threadIdx.x;
  if (i >= n4) return;
  float4 v = reinterpret_cast<const float4*>(in)[i];
  ushort4 o;
  o.x = f2b(v.x); o.y = f2b(v.y); o.z = f2b(v.z); o.w = f2b(v.w);
  reinterpret_cast<ushort4*>(out)[i] = o;
}

// ---------------- transpose + convert: in[rows][cols] f32 -> out[cols][rows] bf16 ----------------
__global__ void transpose_cvt_kernel(const float* __restrict__ in, ushort_t* __restrict__ out,
                                     int rows, int cols) {
  __shared__ float tile[32][33];
  int tx = threadIdx.x & 31, ty = threadIdx.x >> 5;
  int r0 = blockIdx.y * 32, c0 = blockIdx.x * 32;
#pragma unroll
  for (int i = 0; i < 32; i += 8)
    tile[ty + i][tx] = in[(size_t)(r0 + ty + i) * cols + c0 + tx];
  __syncthreads();
#pragma unroll
  for (int i = 0; i < 32; i += 8)
    out[(size_t)(c0 + ty + i) * rows + r0 + tx] = f2b(tile[tx][ty + i]);
}

// ---------------- bf16 GEMM: C = A[M][K] * BT[N][K]^T ----------------
// MODE 0: scatter-write q(*0.125*log2e)/k/vT bf16.  MODE 1: write fp32 C.
template <int MODE>
__global__ __launch_bounds__(256, 2)
void gemm_kernel(const ushort_t* __restrict__ A, const ushort_t* __restrict__ BT,
                 int M, int N, int K,
                 ushort_t* __restrict__ qg, ushort_t* __restrict__ kg,
                 ushort_t* __restrict__ vTg, float* __restrict__ outf) {
  __shared__ ushort_t lA[128 * 64];
  __shared__ ushort_t lB[128 * 64];
  int tid = threadIdx.x;
  int lane = tid & 63, w = tid >> 6;
  int m0 = blockIdx.x * 128, n0 = blockIdx.y * 128;
  int wr = (w >> 1) * 64, wc = (w & 1) * 64;
  int lr = lane & 15, lg = lane >> 4;

  const f32x4 z4 = {0.f, 0.f, 0.f, 0.f};
  f32x4 acc[4][4];
#pragma unroll
  for (int m = 0; m < 4; ++m)
#pragma unroll
    for (int n = 0; n < 4; ++n) acc[m][n] = z4;

  int ktiles = K >> 6;
  for (int kt = 0; kt < ktiles; ++kt) {
    int k0 = kt << 6;
#pragma unroll
    for (int i = 0; i < 4; ++i) {
      int c = i * 256 + tid;
      int row = c >> 3, cc = c & 7;
      gload16(A + (size_t)(m0 + row) * K + k0 + (cc ^ (row & 7)) * 8, lA + c * 8);
    }
#pragma unroll
    for (int i = 0; i < 4; ++i) {
      int c = i * 256 + tid;
      int row = c >> 3, cc = c & 7;
      gload16(BT + (size_t)(n0 + row) * K + k0 + (cc ^ (row & 7)) * 8, lB + c * 8);
    }
    __syncthreads();
#pragma unroll
    for (int kk = 0; kk < 2; ++kk) {
      short8 a[4], b[4];
#pragma unroll
      for (int m = 0; m < 4; ++m) {
        int row = wr + m * 16 + lr, cc = kk * 4 + lg;
        a[m] = *(const short8*)(lA + row * 64 + ((cc ^ (row & 7)) << 3));
      }
#pragma unroll
      for (int n = 0; n < 4; ++n) {
        int row = wc + n * 16 + lr, cc = kk * 4 + lg;
        b[n] = *(const short8*)(lB + row * 64 + ((cc ^ (row & 7)) << 3));
      }
      __builtin_amdgcn_s_setprio(1);
#pragma unroll
      for (int m = 0; m < 4; ++m)
#pragma unroll
        for (int n = 0; n < 4; ++n)
          acc[m][n] = mfma_bf16(a[m], b[n], acc[m][n]);
      __builtin_amdgcn_s_setprio(0);
    }
    __syncthreads();
  }

#pragma unroll
  for (int m = 0; m < 4; ++m)
#pragma unroll
    for (int n = 0; n < 4; ++n)
#pragma unroll
      for (int r = 0; r < 4; ++r) {
        int i = m0 + wr + m * 16 + lg * 4 + r;
        int j = n0 + wc + n * 16 + lr;
        float v = acc[m][n][r];
        if (MODE == 0) {
          int mat = j >> 10, rem = j & 1023;
          int h = rem >> 6, d = rem & 63;
          int b = i >> 12, s = i & 4095;
          int bh = b * HEADS + h;
          // fold 1/sqrt(64) * log2(e) into Q (softmax runs in exp2 domain)
          ushort_t val = f2b(mat == 0 ? v * 0.18033688f : v);
          if (mat == 0)      qg[((size_t)bh * SEQ + s) * DHEAD + d] = val;
          else if (mat == 1) kg[((size_t)bh * SEQ + s) * DHEAD + d] = val;
          else               vTg[((size_t)bh * DHEAD + d) * SEQ + s] = val;
        } else {
          outf[(size_t)i * N + j] = v;
        }
      }
}

// ---------------- paired-tile flash attention, swapped-QK^T (S^T) form ----------------
// One block = (b,h, q-tile pair {31-p, p}); K/V staged ONCE per jt, used by both
// q-tiles. Every block does exactly 33 MFMA-iters -> grid 512 = 2/CU, no tail.
// lK 16KB | lV 16KB | lP 32KB = 64KB. Softmax in exp2 domain, in-lane + 2 shfls.
struct QState {
  short8 qf[2][2];
  float mrow[2], lsum[2];
  f32x4 o[2][4];
};

__device__ __forceinline__ void attn_tile(int jt, int qt, int w, int lr, int lg, int lane,
                                          const ushort_t* lK, const ushort_t* lV,
                                          ushort_t* lP, QState& st) {
  const f32x4 z4 = {0.f, 0.f, 0.f, 0.f};
  f32x4 s[2][8];
#pragma unroll
  for (int qm = 0; qm < 2; ++qm)
#pragma unroll
    for (int kt = 0; kt < 8; ++kt) s[qm][kt] = z4;
#pragma unroll
  for (int kk = 0; kk < 2; ++kk) {
#pragma unroll
    for (int kt = 0; kt < 8; ++kt) {
      int row = kt * 16 + lr;
      short8 kf = *(const short8*)(lK + row * 64 + (((kk * 4 + lg) ^ (row & 7)) << 3));
      __builtin_amdgcn_s_setprio(1);
      s[0][kt] = mfma_bf16(kf, st.qf[0][kk], s[0][kt]);
      s[1][kt] = mfma_bf16(kf, st.qf[1][kk], s[1][kt]);
      __builtin_amdgcn_s_setprio(0);
    }
  }

  if (jt == qt) {  // diagonal: causal mask (local indices, q0==j0)
#pragma unroll
    for (int qm = 0; qm < 2; ++qm) {
      int qgl = w * 32 + qm * 16 + lr;
#pragma unroll
      for (int kt = 0; kt < 8; ++kt)
#pragma unroll
        for (int r = 0; r < 4; ++r)
          if (kt * 16 + lg * 4 + r > qgl) s[qm][kt][r] = -1e30f;
    }
  }

  // online softmax (exp2 domain), defer-max THR=8
  float alv[2] = {1.f, 1.f};
  int resc = 0;
#pragma unroll
  for (int qm = 0; qm < 2; ++qm) {
    float mx = s[qm][0][0];
#pragma unroll
    for (int kt = 0; kt < 8; ++kt)
#pragma unroll
      for (int r = 0; r < 4; ++r) mx = fmaxf(mx, s[qm][kt][r]);
    mx = fmaxf(mx, __shfl_xor(mx, 16));
    mx = fmaxf(mx, __shfl_xor(mx, 32));
    float mo = st.mrow[qm];
    if (!__all(mx - mo <= 8.0f)) {
      float mn = fmaxf(mo, mx);
      float al = exp2_fast(mo - mn);
      st.mrow[qm] = mn;
      st.lsum[qm] *= al;
      alv[qm] = al;
      resc |= (1 << qm);
    }
    float mloc = st.mrow[qm];
    float rs = 0.f;
#pragma unroll
    for (int kt = 0; kt < 8; ++kt)
#pragma unroll
      for (int r = 0; r < 4; ++r) {
        float p = exp2_fast(s[qm][kt][r] - mloc);
        s[qm][kt][r] = p;
        rs += p;
      }
    rs += __shfl_xor(rs, 16);
    rs += __shfl_xor(rs, 32);
    st.lsum[qm] += rs;
  }
  if (resc) {
#pragma unroll
    for (int m = 0; m < 2; ++m)
      if (resc & (1 << m)) {
#pragma unroll
        for (int r = 0; r < 4; ++r) {
          float alo = __shfl(alv[m], (lane & 48) | (lg * 4 + r));
#pragma unroll
          for (int nd = 0; nd < 4; ++nd) st.o[m][nd][r] *= alo;
        }
      }
  }

  // P-write: reg quad = 4 consecutive k for col q -> cvt_pk pairs, ds_write_b64
#pragma unroll
  for (int qm = 0; qm < 2; ++qm) {
    int q = w * 32 + qm * 16 + lr;
#pragma unroll
    for (int kt = 0; kt < 8; ++kt) {
      uint2 pw;
      pw.x = cvt_pk_bf16(s[qm][kt][0], s[qm][kt][1]);
      pw.y = cvt_pk_bf16(s[qm][kt][2], s[qm][kt][3]);
      int c = kt * 2 + (lg >> 1);
      *(uint2*)(lP + q * 128 + (((c ^ (q & 15)) << 3) | ((lg & 1) << 2))) = pw;
    }
  }

  // O += P V (wave-private P rows)
#pragma unroll
  for (int kk = 0; kk < 4; ++kk) {
    short8 a[2];
#pragma unroll
    for (int m = 0; m < 2; ++m) {
      int q = w * 32 + m * 16 + lr;
      a[m] = *(const short8*)(lP + q * 128 + (((kk * 4 + lg) ^ (q & 15)) << 3));
    }
#pragma unroll
    for (int nd = 0; nd < 4; ++nd) {
      int row = nd * 16 + lr;
      short8 b = *(const short8*)(lV + row * 128 + (((kk * 4 + lg) ^ (row & 15)) << 3));
      __builtin_amdgcn_s_setprio(1);
      st.o[0][nd] = mfma_bf16(a[0], b, st.o[0][nd]);
      st.o[1][nd] = mfma_bf16(a[1], b, st.o[1][nd]);
      __builtin_amdgcn_s_setprio(0);
    }
  }
}

__device__ __forceinline__ void attn_epilogue(const QState& st, int q0, int bh,
                                              int w, int lr, int lg, int lane,
                                              ushort_t* __restrict__ og) {
  int b = bh >> 4, h = bh & 15;
#pragma unroll
  for (int m = 0; m < 2; ++m)
#pragma unroll
    for (int r = 0; r < 4; ++r) {
      float ls = __shfl(st.lsum[m], (lane & 48) | (lg * 4 + r));
      float inv = 1.0f / ls;
      int srow = q0 + w * 32 + m * 16 + lg * 4 + r;
#pragma unroll
      for (int nd = 0; nd < 4; ++nd) {
        int col = h * 64 + nd * 16 + lr;
        og[((size_t)b * SEQ + srow) * HID + col] = f2b(st.o[m][nd][r] * inv);
      }
    }
}

__global__ __launch_bounds__(256, 2)
void attn_kernel(const ushort_t* __restrict__ qg, const ushort_t* __restrict__ kg,
                 const ushort_t* __restrict__ vTg, ushort_t* __restrict__ og) {
  __shared__ ushort_t lK[128 * 64];
  __shared__ ushort_t lV[64 * 128];
  __shared__ ushort_t lP[128 * 128];

  int bid = blockIdx.x;
  int wg = (bid & 7) * 64 + (bid >> 3);  // XCD-chunked: 4 bh per XCD
  int bh = wg >> 4;
  int pair = wg & 15;
  int qtA = 31 - pair, qtB = pair;       // qtA >= 16 > qtB
  int q0A = qtA * 128, q0B = qtB * 128;
  const ushort_t* Q = qg + (size_t)bh * SEQ * DHEAD;
  const ushort_t* Kp = kg + (size_t)bh * SEQ * DHEAD;
  const ushort_t* Vt = vTg + (size_t)bh * DHEAD * SEQ;

  int tid = threadIdx.x, lane = tid & 63, w = tid >> 6;
  int lr = lane & 15, lg = lane >> 4;

  // stage both Q tiles into lP (swizzled), hoist fragments, then lP is P-space
#pragma unroll
  for (int i = 0; i < 4; ++i) {
    int c = i * 256 + tid;
    int row = c >> 3, cc = c & 7;
    gload16(Q + (size_t)(q0A + row) * DHEAD + (cc ^ (row & 7)) * 8, lP + c * 8);
    gload16(Q + (size_t)(q0B + row) * DHEAD + (cc ^ (row & 7)) * 8, lP + 8192 + c * 8);
  }
  __syncthreads();
  QState stA, stB;
#pragma unroll
  for (int qm = 0; qm < 2; ++qm)
#pragma unroll
    for (int kk = 0; kk < 2; ++kk) {
      int row = w * 32 + qm * 16 + lr;
      int off = row * 64 + (((kk * 4 + lg) ^ (row & 7)) << 3);
      stA.qf[qm][kk] = *(const short8*)(lP + off);
      stB.qf[qm][kk] = *(const short8*)(lP + 8192 + off);
    }
  asm volatile("s_waitcnt lgkmcnt(0)");  // qf in regs before lP reused for P

  const f32x4 z4 = {0.f, 0.f, 0.f, 0.f};
#pragma unroll
  for (int qm = 0; qm < 2; ++qm) {
    stA.mrow[qm] = -1e30f; stA.lsum[qm] = 0.f;
    stB.mrow[qm] = -1e30f; stB.lsum[qm] = 0.f;
#pragma unroll
    for (int n = 0; n < 4; ++n) { stA.o[qm][n] = z4; stB.o[qm][n] = z4; }
  }

  for (int jt = 0; jt <= qtA; ++jt) {
    int j0 = jt * 128;
#pragma unroll
    for (int i = 0; i < 4; ++i) {
      int c = i * 256 + tid;
      int row = c >> 3, cc = c & 7;
      gload16(Kp + (size_t)(j0 + row) * DHEAD + (cc ^ (row & 7)) * 8, lK + c * 8);
    }
#pragma unroll
    for (int i = 0; i < 4; ++i) {
      int c = i * 256 + tid;
      int d = c >> 4, cc = c & 15;
      gload16(Vt + (size_t)d * SEQ + j0 + (cc ^ (d & 15)) * 8, lV + c * 8);
    }
    __syncthreads();

    attn_tile(jt, qtA, w, lr, lg, lane, lK, lV, lP, stA);
    if (jt <= qtB) attn_tile(jt, qtB, w, lr, lg, lane, lK, lV, lP, stB);

    __syncthreads();  // protect lK/lV/lP before next stage
  }

  attn_epilogue(stA, q0A, bh, w, lr, lg, lane, og);
  attn_epilogue(stB, q0B, bh, w, lr, lg, lane, og);
}

extern "C" void kernel_launch(void* const* d_in, const int* in_sizes, int n_in,
                              void* d_out, int out_size, void* d_ws, size_t ws_size,
                              hipStream_t stream) {
  const float* x = (const float*)d_in[0];
  const float* wqkv = (const float*)d_in[1];
  const float* wout = (const float*)d_in[2];
  float* out = (float*)d_out;

  if (ws_size < 75497472u) return;  // need 75.5 MB scratch

  char* ws = (char*)d_ws;
  ushort_t* xb    = (ushort_t*)(ws);               // 8192x1024 bf16 (reused as attn out)
  ushort_t* wqkvT = (ushort_t*)(ws + 16777216);    // 3072x1024
  ushort_t* woutT = (ushort_t*)(ws + 23068672);    // 1024x1024
  ushort_t* qgb   = (ushort_t*)(ws + 25165824);    // [32][4096][64]
  ushort_t* kgb   = (ushort_t*)(ws + 41943040);    // [32][4096][64]
  ushort_t* vTb   = (ushort_t*)(ws + 58720256);    // [32][64][4096]
  ushort_t* ob    = xb;

  cvt_kernel<<<dim3(8192), dim3(256), 0, stream>>>(x, xb, 2097152);
  transpose_cvt_kernel<<<dim3(96, 32), dim3(256), 0, stream>>>(wqkv, wqkvT, 1024, 3072);
  transpose_cvt_kernel<<<dim3(32, 32), dim3(256), 0, stream>>>(wout, woutT, 1024, 1024);
  gemm_kernel<0><<<dim3(64, 24), dim3(256), 0, stream>>>(xb, wqkvT, 8192, 3072, 1024,
                                                         qgb, kgb, vTb, nullptr);
  attn_kernel<<<dim3(512), dim3(256), 0, stream>>>(qgb, kgb, vTb, ob);
  gemm_kernel<1><<<dim3(64, 8), dim3(256), 0, stream>>>(ob, woutT, 8192, 1024, 1024,
                                                        nullptr, nullptr, nullptr, out);
}